// Round 12
// baseline (132.677 us; speedup 1.0000x reference)
//
#include <hip/hip_runtime.h>
#include <cstdint>
#include <utility>

#define NW 10
#define NL 4

// ============================================================================
// Round 12:
//  - CNOT rings tracked as compile-time GF(2) index maps (round 2).
//  - Lightcone: layer3 keeps Rot{1,5,9}, layer2 drops Rot(7) (round 2).
//  - Product-state init folds encoding RYs + all layer-0 Rots (round 3).
//  - DPP / ds_swizzle / ds_bpermute cross-lane exchange (rounds 4,6).
//  - GF(2) basis relabeling: 9 DS / 9 DPP / 4 local gates (round 11).
//  - NEW: back to ONE sample per wave, but state packed as v2=(re,im) per
//    slot -> 16 v2 = 32 regs (no AGPR split; rounds 7-11 paid ~4.5k
//    accvgpr-copy instrs/wave-pair for the 64-reg sample-paired state).
//    SU(2) update in packed form: n = cm2*z + e1*swap(z) + eo2*p + c1*swap(p)
//    -> 4 VOP3P pk ops/slot (swap/neg fold into op_sel/neg modifiers),
//    halving scalar FMA count while keeping the r4-r6 register footprint.
// ============================================================================

typedef float v2 __attribute__((ext_vector_type(2)));

// ---- compile-time GF(2) relabeling (round 11) -----------------------------
struct Cols10 { unsigned c[10]; };
struct Rows10 { unsigned r[10]; };

constexpr Cols10 TMAT = {{
    0x001, 0x002, 0x004, 0x008,                  // logical 0..3 -> slot bits
    0x070, 0x080, 0x100, 0x130, 0x210, 0x200     // logical 4..9 -> lane mixes
}};

constexpr unsigned tmap(unsigned m) {
    unsigned r = 0;
    for (int b = 0; b < 10; ++b) if ((m >> b) & 1u) r ^= TMAT.c[b];
    return r;
}

constexpr Rows10 invertT() {
    unsigned a[10] = {}, inv[10] = {};
    for (int i = 0; i < 10; ++i) {
        for (int j = 0; j < 10; ++j) a[i] |= ((TMAT.c[j] >> i) & 1u) << j;
        inv[i] = 1u << i;
    }
    for (int col = 0; col < 10; ++col) {
        int piv = -1;
        for (int r2 = col; r2 < 10; ++r2) if ((a[r2] >> col) & 1u) { piv = r2; break; }
        unsigned ta = a[piv]; a[piv] = a[col]; a[col] = ta;
        unsigned ti = inv[piv]; inv[piv] = inv[col]; inv[col] = ti;
        for (int r2 = 0; r2 < 10; ++r2)
            if (r2 != col && ((a[r2] >> col) & 1u)) { a[r2] ^= a[col]; inv[r2] ^= inv[col]; }
    }
    Rows10 R{};
    for (int i = 0; i < 10; ++i) R.r[i] = inv[i];
    return R;
}
constexpr Rows10 RROW = invertT();

constexpr unsigned rmap(unsigned rowmask) {
    unsigned r = 0;
    for (int b = 0; b < 10; ++b) if ((rowmask >> b) & 1u) r ^= RROW.r[b];
    return r;
}

static_assert(RROW.r[0] == 1 && RROW.r[1] == 2 && RROW.r[2] == 4 && RROW.r[3] == 8, "slot rows");
static_assert((RROW.r[4] & 15) == 0 && (RROW.r[5] & 15) == 0 && (RROW.r[6] & 15) == 0 &&
              (RROW.r[7] & 15) == 0 && (RROW.r[8] & 15) == 0 && (RROW.r[9] & 15) == 0, "lane rows");

struct Plan {
    int n;
    uint16_t pmask[40];
    uint16_t rmask[40];
    uint8_t  lw[40];
    uint16_t measmask;
};

constexpr bool keep_rot(int l, int w) {
    if (l <= 1) return true;
    if (l == 2) return w != 7;
    return w == 1 || w == 5 || w == 9;   // l == 3
}

constexpr Plan make_plan() {
    Plan P{};
    unsigned row[10], cI[10];
    for (int b = 0; b < 10; ++b) { row[b] = 1u << b; cI[b] = 1u << b; }
    P.n = 0;
    for (int l = 0; l < NL; ++l) {
        for (int w = 0; w < NW; ++w) {
            if (l > 0 && keep_rot(l, w)) {
                const int b = 9 - w;
                P.pmask[P.n] = (uint16_t)tmap(cI[b]);
                P.rmask[P.n] = (uint16_t)rmap(row[b]);
                P.lw[P.n]    = (uint8_t)(l * NW + w);
                P.n++;
            }
        }
        const int r = l % (NW - 1) + 1;
        for (int w = 0; w < NW; ++w) {
            const int cb = 9 - w, tb = 9 - ((w + r) % NW);
            row[tb] ^= row[cb];
            cI[cb]  ^= cI[tb];
        }
    }
    P.measmask = (uint16_t)rmap(row[0]);
    return P;
}

constexpr Plan PL = make_plan();
constexpr int NROT = 22;
static_assert(PL.n == NROT, "plan size mismatch");

constexpr int LSEL[6] = {
    (int)(RROW.r[9] >> 4), (int)(RROW.r[8] >> 4), (int)(RROW.r[7] >> 4),
    (int)(RROW.r[6] >> 4), (int)(RROW.r[5] >> 4), (int)(RROW.r[4] >> 4)
};

// ---------------------------------------------------------------------------
// cross-lane xor exchange on one 32-bit value (round 11 engine)
// ---------------------------------------------------------------------------
template<int MASK>
__device__ __forceinline__ float swz(float v, int lane) {
    if constexpr (MASK == 1) {
        return __int_as_float(__builtin_amdgcn_mov_dpp(__float_as_int(v), 0xB1, 0xF, 0xF, true));
    } else if constexpr (MASK == 2) {
        return __int_as_float(__builtin_amdgcn_mov_dpp(__float_as_int(v), 0x4E, 0xF, 0xF, true));
    } else if constexpr (MASK == 3) {
        return __int_as_float(__builtin_amdgcn_mov_dpp(__float_as_int(v), 0x1B, 0xF, 0xF, true));
    } else if constexpr (MASK == 7) {
        return __int_as_float(__builtin_amdgcn_mov_dpp(__float_as_int(v), 0x141, 0xF, 0xF, true));
    } else if constexpr (MASK == 15) {
        return __int_as_float(__builtin_amdgcn_mov_dpp(__float_as_int(v), 0x140, 0xF, 0xF, true));
    } else if constexpr (MASK < 32) {
        return __int_as_float(__builtin_amdgcn_ds_swizzle(
            __float_as_int(v), (MASK << 10) | 0x1F));
    } else {
        return __int_as_float(__builtin_amdgcn_ds_bpermute(
            (lane << 2) ^ (MASK << 2), __float_as_int(v)));
    }
}

// exchange a packed (re,im) v2 across lanes: 2 b32 ops on the same engine
template<int MASK>
__device__ __forceinline__ v2 swz2(v2 v, int lane) {
    v2 r;
    r.x = swz<MASK>(v.x, lane);
    r.y = swz<MASK>(v.y, lane);
    return r;
}

__device__ __forceinline__ v2 mkv2(float a, float b) { v2 r; r.x = a; r.y = b; return r; }
__device__ __forceinline__ v2 cswap(v2 v) { return __builtin_shufflevector(v, v, 1, 0); }

// packed SU(2) core: z=(re,im); n = cm2*z + (S?-e1:e1)*swap(z)
//                                 + (S?-eo2:eo2)*p + c1*swap(p)
// cm2=(cmr,cmr), e1=(-bmi,bmi), eo2=(bor,bor), c1=(-coi,coi); S folds at
// compile time after unrolling; fneg folds into VOP3P neg modifiers.
__device__ __forceinline__ v2 rot_core(v2 z, v2 p, v2 cm2, v2 e1, v2 eo2, v2 c1, bool S) {
    const v2 ea = S ? -e1 : e1;
    const v2 eb = S ? -eo2 : eo2;
    return cm2 * z + ea * cswap(z) + eb * p + c1 * cswap(p);
}

template<int G>
__device__ __forceinline__ void apply_rot(v2 (&S)[16],
                                          const float4* __restrict__ rotm,
                                          int lane) {
    constexpr unsigned pm = PL.pmask[G], rm = PL.rmask[G];
    constexpr int pLoc = pm & 15, pLane = (int)(pm >> 4);
    constexpr int rLoc = rm & 15, rLane = (int)(rm >> 4);
    const float4 m = rotm[PL.lw[G]];
    const bool rl = (__popc(lane & rLane) & 1) != 0;   // lane part of role
    const float bmi = rl ? -m.y : m.y;
    const float bor = rl ? -m.z : m.z;
    const v2 cm2 = mkv2(m.x, m.x);
    const v2 e1  = mkv2(-bmi, bmi);
    const v2 eo2 = mkv2(bor, bor);
    const v2 c1  = mkv2(-m.w, m.w);

    if constexpr (pLane == 0) {
        // fully local pair (j, j^pLoc)
#pragma unroll
        for (int j = 0; j < 16; ++j) {
            const int k = j ^ pLoc;
            if (j < k) {
                const v2 zj = S[j], zk = S[k];
                S[j] = rot_core(zj, zk, cm2, e1, eo2, c1,
                                (__builtin_popcount(j & rLoc) & 1) != 0);
                S[k] = rot_core(zk, zj, cm2, e1, eo2, c1,
                                (__builtin_popcount(k & rLoc) & 1) != 0);
            }
        }
    } else if constexpr (pLoc == 0) {
        // partner = same slot, other lane
#pragma unroll
        for (int j = 0; j < 16; ++j) {
            const v2 p = swz2<pLane>(S[j], lane);
            S[j] = rot_core(S[j], p, cm2, e1, eo2, c1,
                            (__builtin_popcount(j & rLoc) & 1) != 0);
        }
    } else {
        // partner = slot j^pLoc at lane^pLane
#pragma unroll
        for (int j = 0; j < 16; ++j) {
            const int k = j ^ pLoc;
            if (j < k) {
                const v2 pj = swz2<pLane>(S[k], lane);
                const v2 pk = swz2<pLane>(S[j], lane);
                S[j] = rot_core(S[j], pj, cm2, e1, eo2, c1,
                                (__builtin_popcount(j & rLoc) & 1) != 0);
                S[k] = rot_core(S[k], pk, cm2, e1, eo2, c1,
                                (__builtin_popcount(k & rLoc) & 1) != 0);
            }
        }
    }
}

template<int... Gs>
__device__ __forceinline__ void apply_all(v2 (&S)[16],
                                          const float4* __restrict__ rotm,
                                          int lane,
                                          std::integer_sequence<int, Gs...>) {
    (apply_rot<Gs>(S, rotm, lane), ...);
}

__device__ __forceinline__ void cmul(float ar, float ai, float br, float bi,
                                     float& cr, float& ci) {
    cr = ar * br - ai * bi;
    ci = ar * bi + ai * br;
}

__global__ __launch_bounds__(256) void vqc_kernel(const float* __restrict__ X,
                                                  const float* __restrict__ W,
                                                  const float* __restrict__ bias,
                                                  float* __restrict__ out,
                                                  int n_samples) {
    __shared__ float4 rotm[NL * NW];
    const int t = threadIdx.x;

    // per-block Rot coefficient prep: only m00, m01 needed (SU(2))
    if (t < NL * NW) {
        const float phi = W[t * 3 + 0], th = W[t * 3 + 1], om = W[t * 3 + 2];
        float sh, ch; sincosf(0.5f * th, &sh, &ch);
        float s0, c0; sincosf(-0.5f * (phi + om), &s0, &c0);   // e^{-i(phi+om)/2}
        float s1, c1; sincosf( 0.5f * (phi - om), &s1, &c1);   // e^{+i(phi-om)/2}
        rotm[t] = make_float4(c0 * ch, s0 * ch, -c1 * sh, -s1 * sh);
    }
    __syncthreads();

    const int wave = (blockIdx.x * blockDim.x + t) >> 6;   // one wave per sample
    const int lane = t & 63;
    if (wave >= n_samples) return;

    // ---- product-state init: per-wire 2-vector v_w = Rot0_w * RY(x_w*pi/2)|0> ----
    // amplitude at physical p = psi_{R(p)}: lane wires select via parity masks
    const float* xp = X + (size_t)wave * NW;
    float v0r[NW], v0i[NW], v1r[NW], v1i[NW];
#pragma unroll
    for (int w = 0; w < NW; ++w) {
        float s, c;
        __sincosf(xp[w] * 0.78539816339744831f, &s, &c);   // half-angle = x*pi/4
        const float4 m = rotm[w];                          // layer 0
        v0r[w] =  m.x * c + m.z * s;
        v0i[w] =  m.y * c + m.w * s;
        v1r[w] = -m.z * c + m.x * s;
        v1i[w] =  m.w * c - m.y * s;
    }
    // lane product H over wires 0..5 (parity-select per relabeling)
    float hr, hi;
    {
        const bool b0 = (__popc(lane & LSEL[0]) & 1) != 0;
        hr = b0 ? v1r[0] : v0r[0];
        hi = b0 ? v1i[0] : v0i[0];
#pragma unroll
        for (int w = 1; w < 6; ++w) {
            const bool b = (__popc(lane & LSEL[w]) & 1) != 0;
            const float br = b ? v1r[w] : v0r[w];
            const float bi = b ? v1i[w] : v0i[w];
            float nr, ni; cmul(hr, hi, br, bi, nr, ni);
            hr = nr; hi = ni;
        }
    }
    // local tables: A over wires 6,7 (slot bits 3,2), B over wires 8,9 (bits 1,0)
    float Ar[4], Ai[4], Br[4], Bi[4];
#pragma unroll
    for (int u = 0; u < 4; ++u) {
        const int hb = (u >> 1) & 1, lb = u & 1;
        cmul(hb ? v1r[6] : v0r[6], hb ? v1i[6] : v0i[6],
             lb ? v1r[7] : v0r[7], lb ? v1i[7] : v0i[7], Ar[u], Ai[u]);
        cmul(hb ? v1r[8] : v0r[8], hb ? v1i[8] : v0i[8],
             lb ? v1r[9] : v0r[9], lb ? v1i[9] : v0i[9], Br[u], Bi[u]);
    }
    float HAr[4], HAi[4];
#pragma unroll
    for (int u = 0; u < 4; ++u) cmul(hr, hi, Ar[u], Ai[u], HAr[u], HAi[u]);

    v2 S[16];
#pragma unroll
    for (int j = 0; j < 16; ++j) {
        float r0, i0;
        cmul(HAr[j >> 2], HAi[j >> 2], Br[j & 3], Bi[j & 3], r0, i0);
        S[j] = mkv2(r0, i0);
    }

    // ---- 22 surviving rotations (layers 1..3); CNOTs are index-map updates ----
    apply_all(S, rotm, lane, std::make_integer_sequence<int, NROT>{});

    // ---- measurement: sign = parity(p_phys & measmask) ----
    constexpr unsigned mm = PL.measmask;
    constexpr int mLoc = mm & 15, mLane = (int)(mm >> 4);
    float acc = 0.0f;
#pragma unroll
    for (int j = 0; j < 16; ++j) {
        const v2 sq = S[j] * S[j];
        const float p = sq.x + sq.y;
        acc += ((__builtin_popcount(j & mLoc) & 1) ? -p : p);
    }
    if (__popc(lane & mLane) & 1) acc = -acc;
    acc += swz<1>(acc, lane);
    acc += swz<2>(acc, lane);
    acc += swz<4>(acc, lane);
    acc += swz<8>(acc, lane);
    acc += swz<16>(acc, lane);
    acc += swz<32>(acc, lane);
    if (lane == 0) out[wave] = acc + bias[0];
}

extern "C" void kernel_launch(void* const* d_in, const int* in_sizes, int n_in,
                              void* d_out, int out_size, void* d_ws, size_t ws_size,
                              hipStream_t stream) {
    const float* X    = (const float*)d_in[0];
    const float* W    = (const float*)d_in[1];
    const float* bias = (const float*)d_in[2];
    float* out = (float*)d_out;
    const int n_samples = in_sizes[0] / NW;               // 16384
    const int threads = 256;                              // 4 waves/block
    const int blocks = (n_samples * 64 + threads - 1) / threads;
    hipLaunchKernelGGL(vqc_kernel, dim3(blocks), dim3(threads), 0, stream,
                       X, W, bias, out, n_samples);
}

// Round 13
// 125.426 us; speedup vs baseline: 1.0578x; 1.0578x over previous
//
#include <hip/hip_runtime.h>
#include <cstdint>
#include <utility>

#define NW 10
#define NL 4

// ============================================================================
// Round 13:  r11 champion + within-layer commuting-gate reorder (exact).
//  - CNOT rings tracked as compile-time GF(2) index maps (round 2).
//  - Lightcone: layer3 keeps Rot{1,5,9}, layer2 drops Rot(7) (round 2).
//  - Product-state init folds encoding RYs + all layer-0 Rots (round 3).
//  - DPP / ds_swizzle / ds_bpermute cross-lane exchange (rounds 4,6).
//  - Sample-pair v2 packing (round 7), GF(2) basis relabeling (round 11).
//  - NEW: rotations within a layer commute (distinct wires; masks constant
//    within the layer) -> reorder each layer to interleave DS-engine gates
//    with DPP/local gates, alternating LDS-pipe and VALU-pipe bursts for
//    better overlap inside the scheduler's slot-level pipelining window.
// ============================================================================

typedef float v2 __attribute__((ext_vector_type(2)));

// ---- compile-time GF(2) relabeling ----------------------------------------
struct Cols10 { unsigned c[10]; };
struct Rows10 { unsigned r[10]; };

constexpr Cols10 TMAT = {{
    0x001, 0x002, 0x004, 0x008,                  // logical 0..3 -> slot bits
    0x070, 0x080, 0x100, 0x130, 0x210, 0x200     // logical 4..9 -> lane mixes
}};

constexpr unsigned tmap(unsigned m) {
    unsigned r = 0;
    for (int b = 0; b < 10; ++b) if ((m >> b) & 1u) r ^= TMAT.c[b];
    return r;
}

constexpr Rows10 invertT() {
    unsigned a[10] = {}, inv[10] = {};
    for (int i = 0; i < 10; ++i) {
        for (int j = 0; j < 10; ++j) a[i] |= ((TMAT.c[j] >> i) & 1u) << j;
        inv[i] = 1u << i;
    }
    for (int col = 0; col < 10; ++col) {
        int piv = -1;
        for (int r2 = col; r2 < 10; ++r2) if ((a[r2] >> col) & 1u) { piv = r2; break; }
        unsigned ta = a[piv]; a[piv] = a[col]; a[col] = ta;
        unsigned ti = inv[piv]; inv[piv] = inv[col]; inv[col] = ti;
        for (int r2 = 0; r2 < 10; ++r2)
            if (r2 != col && ((a[r2] >> col) & 1u)) { a[r2] ^= a[col]; inv[r2] ^= inv[col]; }
    }
    Rows10 R{};
    for (int i = 0; i < 10; ++i) R.r[i] = inv[i];
    return R;
}
constexpr Rows10 RROW = invertT();

constexpr unsigned rmap(unsigned rowmask) {
    unsigned r = 0;
    for (int b = 0; b < 10; ++b) if ((rowmask >> b) & 1u) r ^= RROW.r[b];
    return r;
}

static_assert(RROW.r[0] == 1 && RROW.r[1] == 2 && RROW.r[2] == 4 && RROW.r[3] == 8, "slot rows");
static_assert((RROW.r[4] & 15) == 0 && (RROW.r[5] & 15) == 0 && (RROW.r[6] & 15) == 0 &&
              (RROW.r[7] & 15) == 0 && (RROW.r[8] & 15) == 0 && (RROW.r[9] & 15) == 0, "lane rows");

struct Plan {
    int n;
    uint16_t pmask[40];
    uint16_t rmask[40];
    uint8_t  lw[40];
    uint16_t measmask;
};

constexpr bool keep_rot(int l, int w) {
    if (l <= 1) return true;
    if (l == 2) return w != 7;
    return w == 1 || w == 5 || w == 9;   // l == 3
}

constexpr int engine_class(unsigned pm) {    // 0 = local, 1 = DPP, 2 = DS
    const unsigned lm = pm >> 4;
    if (lm == 0) return 0;
    if (lm == 1 || lm == 2 || lm == 3 || lm == 7 || lm == 15) return 1;
    return 2;
}

constexpr Plan make_plan() {
    Plan P{};
    unsigned row[10], cI[10];
    for (int b = 0; b < 10; ++b) { row[b] = 1u << b; cI[b] = 1u << b; }
    P.n = 0;
    for (int l = 0; l < NL; ++l) {
        // gather this layer's kept gates (masks constant within the layer:
        // cI/row update only at ring boundaries -> reorder is exact)
        unsigned pm[10] = {}, rm[10] = {};
        int lw[10] = {}, cls[10] = {}, cnt = 0;
        for (int w = 0; w < NW; ++w) {
            if (l > 0 && keep_rot(l, w)) {
                const int b = 9 - w;
                pm[cnt] = tmap(cI[b]);
                rm[cnt] = rmap(row[b]);
                lw[cnt] = l * NW + w;
                cls[cnt] = engine_class(pm[cnt]);
                cnt++;
            }
        }
        // interleave DS gates with non-DS gates (alternating pipe bursts)
        int dsIdx[10] = {}, otIdx[10] = {};
        int nds = 0, not_ = 0;
        for (int i = 0; i < cnt; ++i) {
            if (cls[i] == 2) dsIdx[nds++] = i; else otIdx[not_++] = i;
        }
        int di = 0, oi = 0;
        while (di < nds || oi < not_) {
            if (di < nds) {
                const int i = dsIdx[di++];
                P.pmask[P.n] = (uint16_t)pm[i];
                P.rmask[P.n] = (uint16_t)rm[i];
                P.lw[P.n]    = (uint8_t)lw[i];
                P.n++;
            }
            if (oi < not_) {
                const int i = otIdx[oi++];
                P.pmask[P.n] = (uint16_t)pm[i];
                P.rmask[P.n] = (uint16_t)rm[i];
                P.lw[P.n]    = (uint8_t)lw[i];
                P.n++;
            }
        }
        const int r = l % (NW - 1) + 1;
        for (int w = 0; w < NW; ++w) {              // ring: CNOT(w, (w+r)%10)
            const int cb = 9 - w, tb = 9 - ((w + r) % NW);
            row[tb] ^= row[cb];                     // M <- C * M
            cI[cb]  ^= cI[tb];                      // Minv <- Minv * C
        }
    }
    P.measmask = (uint16_t)rmap(row[0]);            // Z on virtual bit 0 (wire 9)
    return P;
}

constexpr Plan PL = make_plan();
constexpr int NROT = 22;
static_assert(PL.n == NROT, "plan size mismatch");

constexpr int LSEL[6] = {
    (int)(RROW.r[9] >> 4), (int)(RROW.r[8] >> 4), (int)(RROW.r[7] >> 4),
    (int)(RROW.r[6] >> 4), (int)(RROW.r[5] >> 4), (int)(RROW.r[4] >> 4)
};

// ---------------------------------------------------------------------------
// cross-lane xor exchange on one 32-bit value
// ---------------------------------------------------------------------------
template<int MASK>
__device__ __forceinline__ float swz(float v, int lane) {
    if constexpr (MASK == 1) {
        return __int_as_float(__builtin_amdgcn_mov_dpp(__float_as_int(v), 0xB1, 0xF, 0xF, true));
    } else if constexpr (MASK == 2) {
        return __int_as_float(__builtin_amdgcn_mov_dpp(__float_as_int(v), 0x4E, 0xF, 0xF, true));
    } else if constexpr (MASK == 3) {
        return __int_as_float(__builtin_amdgcn_mov_dpp(__float_as_int(v), 0x1B, 0xF, 0xF, true));
    } else if constexpr (MASK == 7) {
        return __int_as_float(__builtin_amdgcn_mov_dpp(__float_as_int(v), 0x141, 0xF, 0xF, true));
    } else if constexpr (MASK == 15) {
        return __int_as_float(__builtin_amdgcn_mov_dpp(__float_as_int(v), 0x140, 0xF, 0xF, true));
    } else if constexpr (MASK < 32) {
        return __int_as_float(__builtin_amdgcn_ds_swizzle(
            __float_as_int(v), (MASK << 10) | 0x1F));
    } else {
        return __int_as_float(__builtin_amdgcn_ds_bpermute(
            (lane << 2) ^ (MASK << 2), __float_as_int(v)));
    }
}

template<int MASK>
__device__ __forceinline__ v2 swz2(v2 v, int lane) {
    v2 r;
    r.x = swz<MASK>(v.x, lane);
    r.y = swz<MASK>(v.y, lane);
    return r;
}

__device__ __forceinline__ v2 mkv2(float a, float b) { v2 r; r.x = a; r.y = b; return r; }

__device__ __forceinline__ void cmul2(v2 ar, v2 ai, v2 br, v2 bi, v2& cr, v2& ci) {
    cr = ar * br - ai * bi;
    ci = ar * bi + ai * br;
}

// single amplitude-pair update; S (slot-role parity) folds at compile time.
__device__ __forceinline__ void upd(v2& xr, v2& xi, v2 pr, v2 pi,
                                    float cmr, float coi, float bmi, float bor,
                                    bool S) {
    const float emi = S ? -bmi : bmi;
    const float eor = S ? -bor : bor;
    const v2 nr = cmr * xr - emi * xi + eor * pr - coi * pi;
    const v2 ni = cmr * xi + emi * xr + eor * pi + coi * pr;
    xr = nr; xi = ni;
}

// one masked-pair rotation; SU(2): u11=conj(u00), u10=-conj(u01).
template<int G>
__device__ __forceinline__ void apply_rot(v2 (&sr)[16], v2 (&si)[16],
                                          const float4* __restrict__ rotm,
                                          int lane) {
    constexpr unsigned pm = PL.pmask[G], rm = PL.rmask[G];
    constexpr int pLoc = pm & 15, pLane = (int)(pm >> 4);
    constexpr int rLoc = rm & 15, rLane = (int)(rm >> 4);
    const float4 m = rotm[PL.lw[G]];
    const bool rl = (__popc(lane & rLane) & 1) != 0;   // lane part of role
    const float cmr = m.x, coi = m.w;
    const float bmi = rl ? -m.y : m.y;
    const float bor = rl ? -m.z : m.z;

    if constexpr (pLane == 0) {
        // fully local pair (j, j^pLoc)
#pragma unroll
        for (int j = 0; j < 16; ++j) {
            const int k = j ^ pLoc;
            if (j < k) {
                const v2 ajr = sr[j], aji = si[j];
                const v2 akr = sr[k], aki = si[k];
                upd(sr[j], si[j], akr, aki, cmr, coi, bmi, bor,
                    (__builtin_popcount(j & rLoc) & 1) != 0);
                upd(sr[k], si[k], ajr, aji, cmr, coi, bmi, bor,
                    (__builtin_popcount(k & rLoc) & 1) != 0);
            }
        }
    } else if constexpr (pLoc == 0) {
        // partner = same slot, other lane
#pragma unroll
        for (int j = 0; j < 16; ++j) {
            const v2 pr = swz2<pLane>(sr[j], lane);
            const v2 pi = swz2<pLane>(si[j], lane);
            upd(sr[j], si[j], pr, pi, cmr, coi, bmi, bor,
                (__builtin_popcount(j & rLoc) & 1) != 0);
        }
    } else {
        // partner = slot j^pLoc at lane^pLane
#pragma unroll
        for (int j = 0; j < 16; ++j) {
            const int k = j ^ pLoc;
            if (j < k) {
                const v2 pjr = swz2<pLane>(sr[k], lane);
                const v2 pji = swz2<pLane>(si[k], lane);
                const v2 pkr = swz2<pLane>(sr[j], lane);
                const v2 pki = swz2<pLane>(si[j], lane);
                upd(sr[j], si[j], pjr, pji, cmr, coi, bmi, bor,
                    (__builtin_popcount(j & rLoc) & 1) != 0);
                upd(sr[k], si[k], pkr, pki, cmr, coi, bmi, bor,
                    (__builtin_popcount(k & rLoc) & 1) != 0);
            }
        }
    }
}

template<int... Gs>
__device__ __forceinline__ void apply_all(v2 (&sr)[16], v2 (&si)[16],
                                          const float4* __restrict__ rotm,
                                          int lane,
                                          std::integer_sequence<int, Gs...>) {
    (apply_rot<Gs>(sr, si, rotm, lane), ...);
}

__global__ __launch_bounds__(256, 2) void vqc_kernel(const float* __restrict__ X,
                                                     const float* __restrict__ W,
                                                     const float* __restrict__ bias,
                                                     float* __restrict__ out,
                                                     int n_pairs) {
    __shared__ float4 rotm[NL * NW];
    const int t = threadIdx.x;

    // per-block Rot coefficient prep: only m00, m01 needed (SU(2))
    if (t < NL * NW) {
        const float phi = W[t * 3 + 0], th = W[t * 3 + 1], om = W[t * 3 + 2];
        float sh, ch; sincosf(0.5f * th, &sh, &ch);
        float s0, c0; sincosf(-0.5f * (phi + om), &s0, &c0);   // e^{-i(phi+om)/2}
        float s1, c1; sincosf( 0.5f * (phi - om), &s1, &c1);   // e^{+i(phi-om)/2}
        rotm[t] = make_float4(c0 * ch, s0 * ch, -c1 * sh, -s1 * sh);
    }
    __syncthreads();

    const int wave = (blockIdx.x * blockDim.x + t) >> 6;   // one wave per SAMPLE PAIR
    const int lane = t & 63;
    if (wave >= n_pairs) return;

    // ---- product-state init for both samples: v_w = Rot0_w * RY(x_w*pi/2)|0> ----
    // amplitude at physical p = psi_{R(p)}: lane wires select via parity masks
    const float* xp = X + (size_t)(2 * wave) * NW;        // sample0; sample1 at +NW

    // running lane-product H over wires 0..5 (parity-select per relabeling)
    v2 hr, hi;
#pragma unroll
    for (int w = 0; w < 6; ++w) {
        float s0, c0, s1, c1;
        __sincosf(xp[w]      * 0.78539816339744831f, &s0, &c0);
        __sincosf(xp[w + NW] * 0.78539816339744831f, &s1, &c1);
        const v2 s = mkv2(s0, s1), c = mkv2(c0, c1);
        const float4 m = rotm[w];                          // layer 0
        const v2 a0r = m.x * c + m.z * s;
        const v2 a0i = m.y * c + m.w * s;
        const v2 a1r = m.x * s - m.z * c;
        const v2 a1i = m.w * c - m.y * s;
        const bool b = (__popc(lane & LSEL[w]) & 1) != 0;
        const v2 br = b ? a1r : a0r;
        const v2 bi = b ? a1i : a0i;
        if (w == 0) { hr = br; hi = bi; }
        else {
            v2 nr, ni; cmul2(hr, hi, br, bi, nr, ni);
            hr = nr; hi = ni;
        }
    }
    // wires 6..9 (slot bits identity under T): local tables
    v2 t0r[4], t0i[4], t1r[4], t1i[4];
#pragma unroll
    for (int w = 6; w < 10; ++w) {
        float s0, c0, s1, c1;
        __sincosf(xp[w]      * 0.78539816339744831f, &s0, &c0);
        __sincosf(xp[w + NW] * 0.78539816339744831f, &s1, &c1);
        const v2 s = mkv2(s0, s1), c = mkv2(c0, c1);
        const float4 m = rotm[w];
        t0r[w - 6] = m.x * c + m.z * s;
        t0i[w - 6] = m.y * c + m.w * s;
        t1r[w - 6] = m.x * s - m.z * c;
        t1i[w - 6] = m.w * c - m.y * s;
    }
    // A over wires 6,7 (slot bits 3,2), B over wires 8,9 (slot bits 1,0)
    v2 Ar[4], Ai[4], Br[4], Bi[4];
#pragma unroll
    for (int u = 0; u < 4; ++u) {
        const int hb = (u >> 1) & 1, lb = u & 1;
        cmul2(hb ? t1r[0] : t0r[0], hb ? t1i[0] : t0i[0],
              lb ? t1r[1] : t0r[1], lb ? t1i[1] : t0i[1], Ar[u], Ai[u]);
        cmul2(hb ? t1r[2] : t0r[2], hb ? t1i[2] : t0i[2],
              lb ? t1r[3] : t0r[3], lb ? t1i[3] : t0i[3], Br[u], Bi[u]);
    }
    // HA = H*A, then state[j] = HA[j>>2] * B[j&3]
    v2 HAr[4], HAi[4];
#pragma unroll
    for (int u = 0; u < 4; ++u) cmul2(hr, hi, Ar[u], Ai[u], HAr[u], HAi[u]);

    v2 sr[16], si[16];
#pragma unroll
    for (int j = 0; j < 16; ++j) {
        cmul2(HAr[j >> 2], HAi[j >> 2], Br[j & 3], Bi[j & 3], sr[j], si[j]);
    }

    // ---- 22 surviving rotations (layers 1..3), engine-interleaved order ----
    apply_all(sr, si, rotm, lane, std::make_integer_sequence<int, NROT>{});

    // ---- measurement: sign = parity(p_phys & measmask) ----
    constexpr unsigned mm = PL.measmask;
    constexpr int mLoc = mm & 15, mLane = (int)(mm >> 4);
    v2 acc = mkv2(0.0f, 0.0f);
#pragma unroll
    for (int j = 0; j < 16; ++j) {
        const v2 p = sr[j] * sr[j] + si[j] * si[j];
        if (__builtin_popcount(j & mLoc) & 1) acc -= p; else acc += p;
    }
    if (__popc(lane & mLane) & 1) acc = -acc;
    acc += swz2<1>(acc, lane);
    acc += swz2<2>(acc, lane);
    acc += swz2<4>(acc, lane);
    acc += swz2<8>(acc, lane);
    acc += swz2<16>(acc, lane);
    acc += swz2<32>(acc, lane);
    if (lane == 0) {
        const float b0 = bias[0];
        out[2 * wave]     = acc.x + b0;
        out[2 * wave + 1] = acc.y + b0;
    }
}

extern "C" void kernel_launch(void* const* d_in, const int* in_sizes, int n_in,
                              void* d_out, int out_size, void* d_ws, size_t ws_size,
                              hipStream_t stream) {
    const float* X    = (const float*)d_in[0];
    const float* W    = (const float*)d_in[1];
    const float* bias = (const float*)d_in[2];
    float* out = (float*)d_out;
    const int n_samples = in_sizes[0] / NW;               // 16384
    const int n_pairs = n_samples / 2;                    // 8192 (even batch)
    const int threads = 256;                              // 4 waves/block
    const int blocks = (n_pairs * 64 + threads - 1) / threads;
    hipLaunchKernelGGL(vqc_kernel, dim3(blocks), dim3(threads), 0, stream,
                       X, W, bias, out, n_pairs);
}

// Round 14
// 122.439 us; speedup vs baseline: 1.0836x; 1.0244x over previous
//
#include <hip/hip_runtime.h>
#include <cstdint>
#include <utility>

#define NW 10
#define NL 4

// ============================================================================
// Round 14:  r13 champion + SGPR coefficient path (no LDS in main kernel).
//  - CNOT rings tracked as compile-time GF(2) index maps (round 2).
//  - Lightcone: layer3 keeps Rot{1,5,9}, layer2 drops Rot(7) (round 2).
//  - Product-state init folds encoding RYs + all layer-0 Rots (round 3).
//  - DPP / ds_swizzle / ds_bpermute cross-lane exchange (rounds 4,6).
//  - Sample-pair v2 packing (round 7), GF(2) basis relabeling (round 11).
//  - Engine-interleaved gate order (round 13).
//  - NEW: Rot coefficients are batch-uniform -> computed once by a 1-block
//    prep kernel into d_ws; main kernel reads them at compile-time-constant
//    offsets through a uniform pointer -> s_load_dwordx4 into SGPRs.
//    Removes 22 ds_read_b128/wave from the DS pipe (-23% DS traffic),
//    removes the LDS block + __syncthreads, and frees the per-gate float4
//    VGPR quads (less allocator pressure).
// ============================================================================

typedef float v2 __attribute__((ext_vector_type(2)));

// ---- compile-time GF(2) relabeling ----------------------------------------
struct Cols10 { unsigned c[10]; };
struct Rows10 { unsigned r[10]; };

constexpr Cols10 TMAT = {{
    0x001, 0x002, 0x004, 0x008,                  // logical 0..3 -> slot bits
    0x070, 0x080, 0x100, 0x130, 0x210, 0x200     // logical 4..9 -> lane mixes
}};

constexpr unsigned tmap(unsigned m) {
    unsigned r = 0;
    for (int b = 0; b < 10; ++b) if ((m >> b) & 1u) r ^= TMAT.c[b];
    return r;
}

constexpr Rows10 invertT() {
    unsigned a[10] = {}, inv[10] = {};
    for (int i = 0; i < 10; ++i) {
        for (int j = 0; j < 10; ++j) a[i] |= ((TMAT.c[j] >> i) & 1u) << j;
        inv[i] = 1u << i;
    }
    for (int col = 0; col < 10; ++col) {
        int piv = -1;
        for (int r2 = col; r2 < 10; ++r2) if ((a[r2] >> col) & 1u) { piv = r2; break; }
        unsigned ta = a[piv]; a[piv] = a[col]; a[col] = ta;
        unsigned ti = inv[piv]; inv[piv] = inv[col]; inv[col] = ti;
        for (int r2 = 0; r2 < 10; ++r2)
            if (r2 != col && ((a[r2] >> col) & 1u)) { a[r2] ^= a[col]; inv[r2] ^= inv[col]; }
    }
    Rows10 R{};
    for (int i = 0; i < 10; ++i) R.r[i] = inv[i];
    return R;
}
constexpr Rows10 RROW = invertT();

constexpr unsigned rmap(unsigned rowmask) {
    unsigned r = 0;
    for (int b = 0; b < 10; ++b) if ((rowmask >> b) & 1u) r ^= RROW.r[b];
    return r;
}

static_assert(RROW.r[0] == 1 && RROW.r[1] == 2 && RROW.r[2] == 4 && RROW.r[3] == 8, "slot rows");
static_assert((RROW.r[4] & 15) == 0 && (RROW.r[5] & 15) == 0 && (RROW.r[6] & 15) == 0 &&
              (RROW.r[7] & 15) == 0 && (RROW.r[8] & 15) == 0 && (RROW.r[9] & 15) == 0, "lane rows");

struct Plan {
    int n;
    uint16_t pmask[40];
    uint16_t rmask[40];
    uint8_t  lw[40];
    uint16_t measmask;
};

constexpr bool keep_rot(int l, int w) {
    if (l <= 1) return true;
    if (l == 2) return w != 7;
    return w == 1 || w == 5 || w == 9;   // l == 3
}

constexpr int engine_class(unsigned pm) {    // 0 = local, 1 = DPP, 2 = DS
    const unsigned lm = pm >> 4;
    if (lm == 0) return 0;
    if (lm == 1 || lm == 2 || lm == 3 || lm == 7 || lm == 15) return 1;
    return 2;
}

constexpr Plan make_plan() {
    Plan P{};
    unsigned row[10], cI[10];
    for (int b = 0; b < 10; ++b) { row[b] = 1u << b; cI[b] = 1u << b; }
    P.n = 0;
    for (int l = 0; l < NL; ++l) {
        unsigned pm[10] = {}, rm[10] = {};
        int lw[10] = {}, cls[10] = {}, cnt = 0;
        for (int w = 0; w < NW; ++w) {
            if (l > 0 && keep_rot(l, w)) {
                const int b = 9 - w;
                pm[cnt] = tmap(cI[b]);
                rm[cnt] = rmap(row[b]);
                lw[cnt] = l * NW + w;
                cls[cnt] = engine_class(pm[cnt]);
                cnt++;
            }
        }
        // interleave DS gates with non-DS gates (alternating pipe bursts)
        int dsIdx[10] = {}, otIdx[10] = {};
        int nds = 0, not_ = 0;
        for (int i = 0; i < cnt; ++i) {
            if (cls[i] == 2) dsIdx[nds++] = i; else otIdx[not_++] = i;
        }
        int di = 0, oi = 0;
        while (di < nds || oi < not_) {
            if (di < nds) {
                const int i = dsIdx[di++];
                P.pmask[P.n] = (uint16_t)pm[i];
                P.rmask[P.n] = (uint16_t)rm[i];
                P.lw[P.n]    = (uint8_t)lw[i];
                P.n++;
            }
            if (oi < not_) {
                const int i = otIdx[oi++];
                P.pmask[P.n] = (uint16_t)pm[i];
                P.rmask[P.n] = (uint16_t)rm[i];
                P.lw[P.n]    = (uint8_t)lw[i];
                P.n++;
            }
        }
        const int r = l % (NW - 1) + 1;
        for (int w = 0; w < NW; ++w) {              // ring: CNOT(w, (w+r)%10)
            const int cb = 9 - w, tb = 9 - ((w + r) % NW);
            row[tb] ^= row[cb];                     // M <- C * M
            cI[cb]  ^= cI[tb];                      // Minv <- Minv * C
        }
    }
    P.measmask = (uint16_t)rmap(row[0]);            // Z on virtual bit 0 (wire 9)
    return P;
}

constexpr Plan PL = make_plan();
constexpr int NROT = 22;
static_assert(PL.n == NROT, "plan size mismatch");

constexpr int LSEL[6] = {
    (int)(RROW.r[9] >> 4), (int)(RROW.r[8] >> 4), (int)(RROW.r[7] >> 4),
    (int)(RROW.r[6] >> 4), (int)(RROW.r[5] >> 4), (int)(RROW.r[4] >> 4)
};

// ---------------------------------------------------------------------------
// cross-lane xor exchange on one 32-bit value
// ---------------------------------------------------------------------------
template<int MASK>
__device__ __forceinline__ float swz(float v, int lane) {
    if constexpr (MASK == 1) {
        return __int_as_float(__builtin_amdgcn_mov_dpp(__float_as_int(v), 0xB1, 0xF, 0xF, true));
    } else if constexpr (MASK == 2) {
        return __int_as_float(__builtin_amdgcn_mov_dpp(__float_as_int(v), 0x4E, 0xF, 0xF, true));
    } else if constexpr (MASK == 3) {
        return __int_as_float(__builtin_amdgcn_mov_dpp(__float_as_int(v), 0x1B, 0xF, 0xF, true));
    } else if constexpr (MASK == 7) {
        return __int_as_float(__builtin_amdgcn_mov_dpp(__float_as_int(v), 0x141, 0xF, 0xF, true));
    } else if constexpr (MASK == 15) {
        return __int_as_float(__builtin_amdgcn_mov_dpp(__float_as_int(v), 0x140, 0xF, 0xF, true));
    } else if constexpr (MASK < 32) {
        return __int_as_float(__builtin_amdgcn_ds_swizzle(
            __float_as_int(v), (MASK << 10) | 0x1F));
    } else {
        return __int_as_float(__builtin_amdgcn_ds_bpermute(
            (lane << 2) ^ (MASK << 2), __float_as_int(v)));
    }
}

template<int MASK>
__device__ __forceinline__ v2 swz2(v2 v, int lane) {
    v2 r;
    r.x = swz<MASK>(v.x, lane);
    r.y = swz<MASK>(v.y, lane);
    return r;
}

__device__ __forceinline__ v2 mkv2(float a, float b) { v2 r; r.x = a; r.y = b; return r; }

__device__ __forceinline__ void cmul2(v2 ar, v2 ai, v2 br, v2 bi, v2& cr, v2& ci) {
    cr = ar * br - ai * bi;
    ci = ar * bi + ai * br;
}

// single amplitude-pair update; S (slot-role parity) folds at compile time.
__device__ __forceinline__ void upd(v2& xr, v2& xi, v2 pr, v2 pi,
                                    float cmr, float coi, float bmi, float bor,
                                    bool S) {
    const float emi = S ? -bmi : bmi;
    const float eor = S ? -bor : bor;
    const v2 nr = cmr * xr - emi * xi + eor * pr - coi * pi;
    const v2 ni = cmr * xi + emi * xr + eor * pi + coi * pr;
    xr = nr; xi = ni;
}

// one masked-pair rotation; SU(2): u11=conj(u00), u10=-conj(u01).
// coefficients come from the uniform ws pointer -> s_load_dwordx4 (SGPRs).
template<int G>
__device__ __forceinline__ void apply_rot(v2 (&sr)[16], v2 (&si)[16],
                                          const float4* __restrict__ ws,
                                          int lane) {
    constexpr unsigned pm = PL.pmask[G], rm = PL.rmask[G];
    constexpr int pLoc = pm & 15, pLane = (int)(pm >> 4);
    constexpr int rLoc = rm & 15, rLane = (int)(rm >> 4);
    const float4 m = ws[PL.lw[G]];                     // uniform -> scalar load
    const bool rl = (__popc(lane & rLane) & 1) != 0;   // lane part of role
    const float cmr = m.x, coi = m.w;
    const float bmi = rl ? -m.y : m.y;
    const float bor = rl ? -m.z : m.z;

    if constexpr (pLane == 0) {
        // fully local pair (j, j^pLoc)
#pragma unroll
        for (int j = 0; j < 16; ++j) {
            const int k = j ^ pLoc;
            if (j < k) {
                const v2 ajr = sr[j], aji = si[j];
                const v2 akr = sr[k], aki = si[k];
                upd(sr[j], si[j], akr, aki, cmr, coi, bmi, bor,
                    (__builtin_popcount(j & rLoc) & 1) != 0);
                upd(sr[k], si[k], ajr, aji, cmr, coi, bmi, bor,
                    (__builtin_popcount(k & rLoc) & 1) != 0);
            }
        }
    } else if constexpr (pLoc == 0) {
        // partner = same slot, other lane
#pragma unroll
        for (int j = 0; j < 16; ++j) {
            const v2 pr = swz2<pLane>(sr[j], lane);
            const v2 pi = swz2<pLane>(si[j], lane);
            upd(sr[j], si[j], pr, pi, cmr, coi, bmi, bor,
                (__builtin_popcount(j & rLoc) & 1) != 0);
        }
    } else {
        // partner = slot j^pLoc at lane^pLane
#pragma unroll
        for (int j = 0; j < 16; ++j) {
            const int k = j ^ pLoc;
            if (j < k) {
                const v2 pjr = swz2<pLane>(sr[k], lane);
                const v2 pji = swz2<pLane>(si[k], lane);
                const v2 pkr = swz2<pLane>(sr[j], lane);
                const v2 pki = swz2<pLane>(si[j], lane);
                upd(sr[j], si[j], pjr, pji, cmr, coi, bmi, bor,
                    (__builtin_popcount(j & rLoc) & 1) != 0);
                upd(sr[k], si[k], pkr, pki, cmr, coi, bmi, bor,
                    (__builtin_popcount(k & rLoc) & 1) != 0);
            }
        }
    }
}

template<int... Gs>
__device__ __forceinline__ void apply_all(v2 (&sr)[16], v2 (&si)[16],
                                          const float4* __restrict__ ws,
                                          int lane,
                                          std::integer_sequence<int, Gs...>) {
    (apply_rot<Gs>(sr, si, ws, lane), ...);
}

// ---- prep kernel: batch-uniform Rot coefficients -> d_ws (runs every call) ----
__global__ void prep_kernel(const float* __restrict__ W, float4* __restrict__ ws) {
    const int t = threadIdx.x;
    if (t < NL * NW) {
        const float phi = W[t * 3 + 0], th = W[t * 3 + 1], om = W[t * 3 + 2];
        float sh, ch; sincosf(0.5f * th, &sh, &ch);
        float s0, c0; sincosf(-0.5f * (phi + om), &s0, &c0);   // e^{-i(phi+om)/2}
        float s1, c1; sincosf( 0.5f * (phi - om), &s1, &c1);   // e^{+i(phi-om)/2}
        ws[t] = make_float4(c0 * ch, s0 * ch, -c1 * sh, -s1 * sh);
    }
}

__global__ __launch_bounds__(256, 2) void vqc_kernel(const float* __restrict__ X,
                                                     const float4* __restrict__ ws,
                                                     const float* __restrict__ bias,
                                                     float* __restrict__ out,
                                                     int n_pairs) {
    const int t = threadIdx.x;
    const int wave = (blockIdx.x * blockDim.x + t) >> 6;   // one wave per SAMPLE PAIR
    const int lane = t & 63;
    if (wave >= n_pairs) return;

    // ---- product-state init for both samples: v_w = Rot0_w * RY(x_w*pi/2)|0> ----
    // amplitude at physical p = psi_{R(p)}: lane wires select via parity masks
    const float* xp = X + (size_t)(2 * wave) * NW;        // sample0; sample1 at +NW

    // running lane-product H over wires 0..5 (parity-select per relabeling)
    v2 hr, hi;
#pragma unroll
    for (int w = 0; w < 6; ++w) {
        float s0, c0, s1, c1;
        __sincosf(xp[w]      * 0.78539816339744831f, &s0, &c0);
        __sincosf(xp[w + NW] * 0.78539816339744831f, &s1, &c1);
        const v2 s = mkv2(s0, s1), c = mkv2(c0, c1);
        const float4 m = ws[w];                            // layer 0 (scalar load)
        const v2 a0r = m.x * c + m.z * s;
        const v2 a0i = m.y * c + m.w * s;
        const v2 a1r = m.x * s - m.z * c;
        const v2 a1i = m.w * c - m.y * s;
        const bool b = (__popc(lane & LSEL[w]) & 1) != 0;
        const v2 br = b ? a1r : a0r;
        const v2 bi = b ? a1i : a0i;
        if (w == 0) { hr = br; hi = bi; }
        else {
            v2 nr, ni; cmul2(hr, hi, br, bi, nr, ni);
            hr = nr; hi = ni;
        }
    }
    // wires 6..9 (slot bits identity under T): local tables
    v2 t0r[4], t0i[4], t1r[4], t1i[4];
#pragma unroll
    for (int w = 6; w < 10; ++w) {
        float s0, c0, s1, c1;
        __sincosf(xp[w]      * 0.78539816339744831f, &s0, &c0);
        __sincosf(xp[w + NW] * 0.78539816339744831f, &s1, &c1);
        const v2 s = mkv2(s0, s1), c = mkv2(c0, c1);
        const float4 m = ws[w];
        t0r[w - 6] = m.x * c + m.z * s;
        t0i[w - 6] = m.y * c + m.w * s;
        t1r[w - 6] = m.x * s - m.z * c;
        t1i[w - 6] = m.w * c - m.y * s;
    }
    // A over wires 6,7 (slot bits 3,2), B over wires 8,9 (slot bits 1,0)
    v2 Ar[4], Ai[4], Br[4], Bi[4];
#pragma unroll
    for (int u = 0; u < 4; ++u) {
        const int hb = (u >> 1) & 1, lb = u & 1;
        cmul2(hb ? t1r[0] : t0r[0], hb ? t1i[0] : t0i[0],
              lb ? t1r[1] : t0r[1], lb ? t1i[1] : t0i[1], Ar[u], Ai[u]);
        cmul2(hb ? t1r[2] : t0r[2], hb ? t1i[2] : t0i[2],
              lb ? t1r[3] : t0r[3], lb ? t1i[3] : t0i[3], Br[u], Bi[u]);
    }
    // HA = H*A, then state[j] = HA[j>>2] * B[j&3]
    v2 HAr[4], HAi[4];
#pragma unroll
    for (int u = 0; u < 4; ++u) cmul2(hr, hi, Ar[u], Ai[u], HAr[u], HAi[u]);

    v2 sr[16], si[16];
#pragma unroll
    for (int j = 0; j < 16; ++j) {
        cmul2(HAr[j >> 2], HAi[j >> 2], Br[j & 3], Bi[j & 3], sr[j], si[j]);
    }

    // ---- 22 surviving rotations (layers 1..3), engine-interleaved order ----
    apply_all(sr, si, ws, lane, std::make_integer_sequence<int, NROT>{});

    // ---- measurement: sign = parity(p_phys & measmask) ----
    constexpr unsigned mm = PL.measmask;
    constexpr int mLoc = mm & 15, mLane = (int)(mm >> 4);
    v2 acc = mkv2(0.0f, 0.0f);
#pragma unroll
    for (int j = 0; j < 16; ++j) {
        const v2 p = sr[j] * sr[j] + si[j] * si[j];
        if (__builtin_popcount(j & mLoc) & 1) acc -= p; else acc += p;
    }
    if (__popc(lane & mLane) & 1) acc = -acc;
    acc += swz2<1>(acc, lane);
    acc += swz2<2>(acc, lane);
    acc += swz2<4>(acc, lane);
    acc += swz2<8>(acc, lane);
    acc += swz2<16>(acc, lane);
    acc += swz2<32>(acc, lane);
    if (lane == 0) {
        const float b0 = bias[0];
        out[2 * wave]     = acc.x + b0;
        out[2 * wave + 1] = acc.y + b0;
    }
}

extern "C" void kernel_launch(void* const* d_in, const int* in_sizes, int n_in,
                              void* d_out, int out_size, void* d_ws, size_t ws_size,
                              hipStream_t stream) {
    const float* X    = (const float*)d_in[0];
    const float* W    = (const float*)d_in[1];
    const float* bias = (const float*)d_in[2];
    float* out = (float*)d_out;
    float4* ws = (float4*)d_ws;                           // 40 x float4 = 640 B
    const int n_samples = in_sizes[0] / NW;               // 16384
    const int n_pairs = n_samples / 2;                    // 8192 (even batch)
    const int threads = 256;                              // 4 waves/block
    const int blocks = (n_pairs * 64 + threads - 1) / threads;
    hipLaunchKernelGGL(prep_kernel, dim3(1), dim3(64), 0, stream, W, ws);
    hipLaunchKernelGGL(vqc_kernel, dim3(blocks), dim3(threads), 0, stream,
                       X, (const float4*)ws, bias, out, n_pairs);
}